// Round 7
// baseline (4855.272 us; speedup 1.0000x reference)
//
#include <hip/hip_runtime.h>
#include <float.h>

#define N_PTS   50000
#define M_CENT  2048
#define K_LOC   32
#define C_CH    128

typedef unsigned long long u64;
typedef unsigned int u32;

// ---------------- FPS: single-block, chunk-pruned ----------------
// R2-R6 established on hardware that EVERY cross-CU store (plain, sc0, sc1,
// atomic) reaches the memory-side coherence point (WRITE_SIZE == slot
// traffic, byte-exact across flag variants) -> multi-block FPS has a
// ~2500-3000 cyc/iter fabric rendezvous floor (measured 3430-3506 us across
// all protocol variants). So: remove the rendezvous entirely.
//
// Points are partitioned into <=64-pt spatial chunks (10^3 grid cells,
// split at 64). Per chunk: tight bbox (actual points) and key =
// (maxdist_bits<<32) | ~min_orig_idx. Per iteration, chunk is EXACTLY
// skippable when 0.999 * LB(bbox, c) >= chunk_maxdist, because then for
// every point j in the chunk: d2_ref(j,c) >= LB_real*(1-eps) >= 0.999*LB_f
// >= chunk_max >= dist_j -> min(dist_j, d2) == dist_j bit-identically.
// (multiplicative 1e-3 margin >> ~10 ulp of accumulated f32 rounding).
// Non-pruned chunks recompute d2 with the EXACT reference arithmetic
// (fsub/fmul/fadd, ((xx+yy)+zz)) -> dist array evolution and winner
// sequence are bit-identical to the reference; ties resolve to min orig
// index via the ~idx key (u64 max).
//
// Single 1024-thread block on one CU: all sync is __syncthreads, all hot
// data LDS (keys/ranges) or L1/L2 (coords/dists). No spin loops anywhere ->
// no hang mode; worst case (pathological point distribution) is slow, not
// wrong.
#define G_DIM   10
#define N_CELL  (G_DIM*G_DIM*G_DIM)   // 1000
#define NC_MAX  2048                  // >= 1000 + 50000/64 = 1782
#define NP_PAD  50176                 // padded array stride (64-multiple)
#define FPS1_NT 1024
#define NWAVE   (FPS1_NT/64)          // 16

__device__ __forceinline__ int cell_of(float x, float y, float z) {
  int a = (int)(x * (float)G_DIM);
  int b = (int)(y * (float)G_DIM);
  int c = (int)(z * (float)G_DIM);
  a = a < 0 ? 0 : (a > G_DIM-1 ? G_DIM-1 : a);
  b = b < 0 ? 0 : (b > G_DIM-1 ? G_DIM-1 : b);
  c = c < 0 ? 0 : (c > G_DIM-1 ? G_DIM-1 : c);
  return (a * G_DIM + b) * G_DIM + c;
}

// ---- DPP wave-wide reductions (ctrl must be a literal constant) ----
template <int CTRL>
__device__ __forceinline__ u32 dppmov_u(u32 v) {
  return (u32)__builtin_amdgcn_update_dpp((int)v, (int)v, CTRL, 0xf, 0xf, false);
}
template <int CTRL>
__device__ __forceinline__ float dppmov_f(float v) {
  return __int_as_float(
      __builtin_amdgcn_update_dpp(__float_as_int(v), __float_as_int(v),
                                  CTRL, 0xf, 0xf, false));
}
__device__ __forceinline__ float wave_max_f32(float v) {
  v = fmaxf(v, dppmov_f<0x111>(v));
  v = fmaxf(v, dppmov_f<0x112>(v));
  v = fmaxf(v, dppmov_f<0x114>(v));
  v = fmaxf(v, dppmov_f<0x118>(v));
  v = fmaxf(v, dppmov_f<0x142>(v));
  v = fmaxf(v, dppmov_f<0x143>(v));
  return __int_as_float(__builtin_amdgcn_readlane(__float_as_int(v), 63));
}
__device__ __forceinline__ float wave_min_f32(float v) {
  v = fminf(v, dppmov_f<0x111>(v));
  v = fminf(v, dppmov_f<0x112>(v));
  v = fminf(v, dppmov_f<0x114>(v));
  v = fminf(v, dppmov_f<0x118>(v));
  v = fminf(v, dppmov_f<0x142>(v));
  v = fminf(v, dppmov_f<0x143>(v));
  return __int_as_float(__builtin_amdgcn_readlane(__float_as_int(v), 63));
}
template <int CTRL>
__device__ __forceinline__ u64 dpp_u64(u64 v) {
  u32 hi = dppmov_u<CTRL>((u32)(v >> 32));
  u32 lo = dppmov_u<CTRL>((u32)v);
  return ((u64)hi << 32) | (u64)lo;
}
__device__ __forceinline__ u64 wave_max_u64(u64 v) {
  u64 t;
  t = dpp_u64<0x111>(v); if (t > v) v = t;
  t = dpp_u64<0x112>(v); if (t > v) v = t;
  t = dpp_u64<0x114>(v); if (t > v) v = t;
  t = dpp_u64<0x118>(v); if (t > v) v = t;
  t = dpp_u64<0x142>(v); if (t > v) v = t;
  t = dpp_u64<0x143>(v); if (t > v) v = t;
  u32 rh = (u32)__builtin_amdgcn_readlane((int)(v >> 32), 63);
  u32 rl = (u32)__builtin_amdgcn_readlane((int)(v & 0xFFFFFFFFull), 63);
  return ((u64)rh << 32) | (u64)rl;
}

// ---------------- prep kernels ----------------
__global__ void init_zero_kernel(int* __restrict__ p, int n) {
  int t = blockIdx.x * blockDim.x + threadIdx.x;
  if (t < n) p[t] = 0;
}

__global__ void hist_kernel(const float* __restrict__ pos,
                            int* __restrict__ cellcnt) {
  int n = blockIdx.x * blockDim.x + threadIdx.x;
  if (n >= N_PTS) return;
  atomicAdd(&cellcnt[cell_of(pos[3*n], pos[3*n+1], pos[3*n+2])], 1);
}

__global__ __launch_bounds__(1024) void scan_kernel(
    const int* __restrict__ cellcnt, int* __restrict__ cursor,
    int2* __restrict__ rng, int* __restrict__ ncp)
{
  __shared__ int s[1024];
  const int tid = threadIdx.x;
  int cnt = (tid < N_CELL) ? cellcnt[tid] : 0;
  s[tid] = cnt;
  __syncthreads();
  for (int off = 1; off < 1024; off <<= 1) {        // inclusive scan (counts)
    int add = (tid >= off) ? s[tid - off] : 0;
    __syncthreads();
    s[tid] += add;
    __syncthreads();
  }
  int pofs = s[tid] - cnt;                          // exclusive point offset
  int nch  = (cnt + 63) >> 6;                       // chunks for this cell
  __syncthreads();
  s[tid] = nch;
  __syncthreads();
  for (int off = 1; off < 1024; off <<= 1) {        // inclusive scan (chunks)
    int add = (tid >= off) ? s[tid - off] : 0;
    __syncthreads();
    s[tid] += add;
    __syncthreads();
  }
  int chbase = s[tid] - nch;
  if (tid < N_CELL) {
    cursor[tid] = pofs;
    for (int k = 0; k < nch; k++) {
      int rem = cnt - (k << 6);
      rng[chbase + k] = make_int2(pofs + (k << 6), rem < 64 ? rem : 64);
    }
  }
  if (tid == 1023) *ncp = s[1023];                  // total chunk count
}

__global__ void scatter_kernel(const float* __restrict__ pos,
    int* __restrict__ cursor,
    float* __restrict__ spx, float* __restrict__ spy,
    float* __restrict__ spz, int* __restrict__ sidx)
{
  int n = blockIdx.x * blockDim.x + threadIdx.x;
  if (n >= N_PTS) return;
  float x = pos[3*n], y = pos[3*n+1], z = pos[3*n+2];
  int p = atomicAdd(&cursor[cell_of(x, y, z)], 1);
  spx[p] = x; spy[p] = y; spz[p] = z; sidx[p] = n;
}

__global__ __launch_bounds__(64) void bbox_kernel(
    const float* __restrict__ spx, const float* __restrict__ spy,
    const float* __restrict__ spz, const int2* __restrict__ rng,
    const int* __restrict__ ncp,
    float4* __restrict__ bb_lo, float4* __restrict__ bb_hi,
    float* __restrict__ sdist)
{
  const int b = blockIdx.x, lane = threadIdx.x;
  int gid = b * 64 + lane;
  if (gid < N_PTS) sdist[gid] = FLT_MAX;            // matches finfo(f32).max
  int NC = *ncp;
  if (b >= NC) return;
  int2 rc = rng[b];
  bool v = lane < rc.y;
  int g = rc.x + lane;
  float x = v ? spx[g] : 0.f, y = v ? spy[g] : 0.f, z = v ? spz[g] : 0.f;
  float lx = wave_min_f32(v ? x :  FLT_MAX);
  float ly = wave_min_f32(v ? y :  FLT_MAX);
  float lz = wave_min_f32(v ? z :  FLT_MAX);
  float hx = wave_max_f32(v ? x : -FLT_MAX);
  float hy = wave_max_f32(v ? y : -FLT_MAX);
  float hz = wave_max_f32(v ? z : -FLT_MAX);
  if (lane == 0) {
    bb_lo[b] = make_float4(lx, ly, lz, 0.f);
    bb_hi[b] = make_float4(hx, hy, hz, 0.f);
  }
}

// ---------------- the FPS kernel ----------------
__global__ __launch_bounds__(FPS1_NT) void fps_kernel(
    const float* __restrict__ pos,
    const float* __restrict__ spx, const float* __restrict__ spy,
    const float* __restrict__ spz, const int* __restrict__ sidx,
    float* __restrict__ sdist, const int2* __restrict__ rng,
    const float4* __restrict__ bb_lo, const float4* __restrict__ bb_hi,
    const int* __restrict__ ncp, float* __restrict__ cent_out)
{
  __shared__ u64  l_key[NC_MAX];     // (maxdist_bits<<32) | ~minidx
  __shared__ int2 l_rng[NC_MAX];     // chunk (start, cnt)
  __shared__ int  l_act[NC_MAX];     // compacted active chunk ids
  __shared__ u64  l_red[NWAVE];
  __shared__ int  l_nact;
  __shared__ u32  l_win;

  const int tid = threadIdx.x, lane = tid & 63, wv = tid >> 6;
  const int NC = *ncp;               // <= 1000 + 782 < NC_MAX structurally

  for (int c = tid; c < NC; c += FPS1_NT) {
    l_rng[c] = rng[c];
    l_key[c] = ((u64)0x7F7FFFFFu) << 32;   // maxdist = FLT_MAX: force update
  }
  __syncthreads();

  // iteration 0 centroid = point 0 (deterministic start, matches reference)
  float cx = pos[0], cy = pos[1], cz = pos[2];

  for (int i = 0; i < M_CENT; i++) {
    if (tid == 0) {
      cent_out[3*i+0] = cx; cent_out[3*i+1] = cy; cent_out[3*i+2] = cz;
      l_nact = 0;
    }
    if (i == M_CENT - 1) break;      // last winner never consumed (uniform)
    __syncthreads();

    // ---- Phase A: prune-eval + wave-ballot compaction ----
    for (int c0 = 0; c0 < NC; c0 += FPS1_NT) {
      int c = c0 + tid;
      bool act = false;
      if (c < NC) {
        float cmax = __uint_as_float((u32)(l_key[c] >> 32));
        float4 lo = bb_lo[c], hi = bb_hi[c];
        float ax = fmaxf(fmaxf(__fsub_rn(lo.x, cx), __fsub_rn(cx, hi.x)), 0.f);
        float ay = fmaxf(fmaxf(__fsub_rn(lo.y, cy), __fsub_rn(cy, hi.y)), 0.f);
        float az = fmaxf(fmaxf(__fsub_rn(lo.z, cz), __fsub_rn(cz, hi.z)), 0.f);
        float LB = (ax*ax + ay*ay + az*az) * 0.999f;  // conservative margin
        act = LB < cmax;             // NOT provably-skippable -> update
      }
      u64 m = __ballot(act);
      if (m) {
        int leader = __ffsll((long long)m) - 1;
        int base = 0;
        if (lane == leader) base = atomicAdd(&l_nact, __popcll(m));
        base = __shfl(base, leader, 64);
        if (act)
          l_act[base + __popcll(m & ((1ull << lane) - 1ull))] = c;
      }
    }
    __syncthreads();

    // ---- Phase B: update active chunks, one wave per chunk ----
    int nact = l_nact;
    for (int a = wv; a < nact; a += NWAVE) {
      int c = l_act[a];
      int2 rc = l_rng[c];
      u64 key = 0ull;
      if (lane < rc.y) {
        int g = rc.x + lane;
        // exact reference arithmetic: no FMA, ((dx^2+dy^2)+dz^2)
        float dx = __fsub_rn(spx[g], cx);
        float dy = __fsub_rn(spy[g], cy);
        float dz = __fsub_rn(spz[g], cz);
        float d2 = __fadd_rn(__fadd_rn(__fmul_rn(dx, dx), __fmul_rn(dy, dy)),
                             __fmul_rn(dz, dz));
        float d = fminf(sdist[g], d2);
        sdist[g] = d;
        key = ((u64)__float_as_uint(d) << 32) | (u64)(u32)(~(u32)sidx[g]);
      }
      key = wave_max_u64(key);
      if (lane == 0) l_key[c] = key;
    }
    __syncthreads();

    // ---- Phase C: winner = max over all chunk keys ----
    u64 best = 0ull;
    for (int c = tid; c < NC; c += FPS1_NT) {
      u64 k = l_key[c];
      if (k > best) best = k;
    }
    best = wave_max_u64(best);
    if (lane == 0) l_red[wv] = best;
    __syncthreads();
    if (wv == 0) {
      u64 b = (lane < NWAVE) ? l_red[lane] : 0ull;
      b = wave_max_u64(b);
      if (lane == 0) l_win = ~(u32)(b & 0xFFFFFFFFull);
    }
    __syncthreads();
    u32 widx = l_win;                // orig index of winner
    cx = pos[3*widx+0]; cy = pos[3*widx+1]; cz = pos[3*widx+2];
  }
}

// ---------------- Ball query ----------------
#define BQ_NT  256
#define BQ_CAP 2048   // expected ~209 candidates/centroid; huge safety margin

__global__ __launch_bounds__(BQ_NT) void ballq_kernel(
    const float* __restrict__ pos,
    const float* __restrict__ cent,   // centroid coords (from d_out)
    int* __restrict__ nbr,            // [M_CENT*K_LOC]
    int* __restrict__ nsel)           // [M_CENT]
{
  __shared__ float s_d2[BQ_CAP];
  __shared__ int   s_idx[BQ_CAP];
  __shared__ int   s_count;
  __shared__ u64   s_red[BQ_NT/64];
  __shared__ u64   s_win;

  const int m = blockIdx.x, tid = threadIdx.x;
  if (tid == 0) s_count = 0;
  __syncthreads();
  const float cx = cent[3*m+0], cy = cent[3*m+1], cz = cent[3*m+2];

  for (int n = tid; n < N_PTS; n += BQ_NT) {
    float dx = __fsub_rn(cx, pos[3*n+0]);
    float dy = __fsub_rn(cy, pos[3*n+1]);
    float dz = __fsub_rn(cz, pos[3*n+2]);
    float d2 = __fadd_rn(__fadd_rn(__fmul_rn(dx,dx), __fmul_rn(dy,dy)),
                         __fmul_rn(dz,dz));
    if (d2 <= 0.01f) {   // same f32 value as (float)(0.1*0.1)
      int p = atomicAdd(&s_count, 1);
      if (p < BQ_CAP) { s_d2[p] = d2; s_idx[p] = n; }
    }
  }
  __syncthreads();
  int cnt = s_count; if (cnt > BQ_CAP) cnt = BQ_CAP;
  int ns = cnt < K_LOC ? cnt : K_LOC;

  // exact top_k semantics: k smallest d2, ties -> smaller index
  for (int sel = 0; sel < ns; sel++) {
    u64 best = ~0ull;
    for (int p = tid; p < cnt; p += BQ_NT) {
      u64 pk = ((u64)__float_as_uint(s_d2[p]) << 32) | (u64)(u32)s_idx[p];
      if (pk < best) best = pk;
    }
#pragma unroll
    for (int off = 32; off >= 1; off >>= 1) {
      u64 o = __shfl_down(best, off, 64);
      if (o < best) best = o;
    }
    if ((tid & 63) == 0) s_red[tid >> 6] = best;
    __syncthreads();
    if (tid < 64) {
      best = (tid < BQ_NT/64) ? s_red[tid] : ~0ull;
#pragma unroll
      for (int off = 2; off >= 1; off >>= 1) {
        u64 o = __shfl_down(best, off, 64);
        if (o < best) best = o;
      }
      if (tid == 0) s_win = best;
    }
    __syncthreads();
    int widx = (int)(u32)(s_win & 0xFFFFFFFFull);
    if (tid == 0) nbr[m*K_LOC + sel] = widx;
    for (int p = tid; p < cnt; p += BQ_NT) {
      if (s_idx[p] == widx) s_d2[p] = FLT_MAX;   // remove winner
    }
    __syncthreads();
  }
  if (tid == 0) nsel[m] = ns;
}

// ---------------- Gather + max-pool + channel mix ----------------
// Max over the valid selected set == reference (fallback idx is the nearest
// valid neighbor, already a member of the set).
__global__ __launch_bounds__(C_CH) void pool_mix_kernel(
    const float* __restrict__ fs,   // (N,128,1)
    const float* __restrict__ fv,   // (N,128,3)
    const float* __restrict__ Ws,
    const float* __restrict__ Wv,
    const float* __restrict__ bs,
    const float* __restrict__ bv,
    const int* __restrict__ nbr,
    const int* __restrict__ nsel,
    float* __restrict__ out_s,      // (M,128,1)
    float* __restrict__ out_v)      // (M,128,3)
{
  __shared__ float ps[C_CH];
  __shared__ float pv[C_CH*3];
  const int m = blockIdx.x, o = threadIdx.x;
  const int ns = nsel[m];
  float mS = -FLT_MAX, m0 = -FLT_MAX, m1 = -FLT_MAX, m2 = -FLT_MAX;
  for (int j = 0; j < ns; j++) {
    int n = nbr[m*K_LOC + j];
    mS = fmaxf(mS, fs[(size_t)n*C_CH + o]);
    const float* r = fv + (size_t)n*(C_CH*3) + 3*o;
    m0 = fmaxf(m0, r[0]); m1 = fmaxf(m1, r[1]); m2 = fmaxf(m2, r[2]);
  }
  ps[o] = mS; pv[3*o+0] = m0; pv[3*o+1] = m1; pv[3*o+2] = m2;
  __syncthreads();
  float aS = bs[o];
  float a0 = bv[o], a1 = bv[o], a2 = bv[o];
  for (int cc = 0; cc < C_CH; cc++) {
    float w1 = Ws[cc*C_CH + o];
    float w2 = Wv[cc*C_CH + o];
    aS = fmaf(ps[cc], w1, aS);
    a0 = fmaf(pv[3*cc+0], w2, a0);
    a1 = fmaf(pv[3*cc+1], w2, a1);
    a2 = fmaf(pv[3*cc+2], w2, a2);
  }
  out_s[(size_t)m*C_CH + o] = aS;
  float* ov = out_v + (size_t)m*(C_CH*3) + 3*o;
  ov[0] = a0; ov[1] = a1; ov[2] = a2;
}

extern "C" void kernel_launch(void* const* d_in, const int* in_sizes, int n_in,
                              void* d_out, int out_size, void* d_ws, size_t ws_size,
                              hipStream_t stream) {
  (void)in_sizes; (void)n_in; (void)out_size; (void)ws_size;
  const float* pos = (const float*)d_in[0];
  const float* fs  = (const float*)d_in[1];
  const float* fv  = (const float*)d_in[2];
  const float* Ws  = (const float*)d_in[3];
  const float* Wv  = (const float*)d_in[4];
  const float* bs  = (const float*)d_in[5];
  const float* bv  = (const float*)d_in[6];

  float* out      = (float*)d_out;
  float* cent_out = out;                               // 2048*3
  float* out_s    = out + 3*M_CENT;                    // 2048*128
  float* out_v    = out + 3*M_CENT + M_CENT*C_CH;      // 2048*128*3

  // workspace layout (all offsets 256B-aligned)
  char* ws = (char*)d_ws;
  size_t off = 0;
  float* spx   = (float*)(ws + off); off += (size_t)NP_PAD * 4;   // 200704
  float* spy   = (float*)(ws + off); off += (size_t)NP_PAD * 4;
  float* spz   = (float*)(ws + off); off += (size_t)NP_PAD * 4;
  int*   sidx  = (int*)  (ws + off); off += (size_t)NP_PAD * 4;
  float* sdist = (float*)(ws + off); off += (size_t)NP_PAD * 4;
  int*   cellcnt = (int*)(ws + off); off += 1024 * 4;
  int*   cursor  = (int*)(ws + off); off += 1024 * 4;
  int*   ncp     = (int*)(ws + off); off += 256;
  int2*  rng     = (int2*)(ws + off); off += (size_t)NC_MAX * 8;
  float4* bb_lo  = (float4*)(ws + off); off += (size_t)NC_MAX * 16;
  float4* bb_hi  = (float4*)(ws + off); off += (size_t)NC_MAX * 16;
  int*   nbr     = (int*)(ws + off); off += (size_t)M_CENT * K_LOC * 4;
  int*   nsel    = (int*)(ws + off); off += (size_t)M_CENT * 4;

  // zero cellcnt + cursor + ncp (contiguous: 1024+1024+64 ints)
  init_zero_kernel<<<(2112 + 255)/256, 256, 0, stream>>>(cellcnt, 2112);
  hist_kernel<<<(N_PTS + 255)/256, 256, 0, stream>>>(pos, cellcnt);
  scan_kernel<<<1, 1024, 0, stream>>>(cellcnt, cursor, rng, ncp);
  scatter_kernel<<<(N_PTS + 255)/256, 256, 0, stream>>>(pos, cursor,
                                                        spx, spy, spz, sidx);
  bbox_kernel<<<NC_MAX, 64, 0, stream>>>(spx, spy, spz, rng, ncp,
                                         bb_lo, bb_hi, sdist);
  fps_kernel<<<1, FPS1_NT, 0, stream>>>(pos, spx, spy, spz, sidx, sdist,
                                        rng, bb_lo, bb_hi, ncp, cent_out);
  ballq_kernel<<<M_CENT, BQ_NT, 0, stream>>>(pos, cent_out, nbr, nsel);
  pool_mix_kernel<<<M_CENT, C_CH, 0, stream>>>(fs, fv, Ws, Wv, bs, bv,
                                               nbr, nsel, out_s, out_v);
}

// Round 8
// 4748.134 us; speedup vs baseline: 1.0226x; 1.0226x over previous
//
#include <hip/hip_runtime.h>
#include <float.h>

#define N_PTS   50000
#define M_CENT  2048
#define K_LOC   32
#define C_CH    128

typedef unsigned long long u64;
typedef unsigned int u32;

// ---------------- FPS: single-block, chunk-pruned (R8 tuning) ----------------
// R2-R6: every cross-CU store reaches the memory-side coherence point ->
// multi-block FPS has a ~2800 cyc/iter fabric floor (3430-3506 us measured).
// R7 proved the single-block chunk-pruned design EXACT (absmax 0.0) but was
// issue-bound at 5400 cyc/iter: u64 DPP reduce per chunk, half-empty waves
// (10^3 grid -> avg 28 pts/chunk), and 2-pass A/C scans (NC=1025 > 1024).
//
// R8: 8^3 grid with <=128-pt chunks (2 pts/lane) -> NC <= 903 (single-pass
// A/C, full waves, ~3x fewer chunks per covered point); Phase B reduce is
// f32 wave-max (12 ops) + u32 tie-min chain (18 ops) instead of u64 chain
// (~40); points packed as float4 (x,y,z,bitcast origidx) -> 1 dwordx4 load.
//
// Exactness (unchanged proof, R7-verified): chunk skippable when
// 0.999*LB(bbox,c) >= chunk_max  =>  for all j: d2_ref(j,c) >= dist_j ->
// min is a no-op bit-identically (1e-3 margin >> f32 rounding slack).
// Non-pruned chunks use the EXACT reference arithmetic (fsub/fmul/fadd,
// ((xx+yy)+zz)) -> dist evolution and winner sequence bit-identical; ties
// resolve to min orig idx via key = (maxdist_bits<<32) | ~minidx.
#define G_DIM   8
#define N_CELL  (G_DIM*G_DIM*G_DIM)   // 512
#define CHUNK_CAP 128
#define NC_MAX  1024                  // >= 512 + 50000/128 = 903 worst case
#define NP_PAD  50176                 // padded array stride (64-multiple)
#define FPS1_NT 1024
#define NWAVE   (FPS1_NT/64)          // 16

__device__ __forceinline__ int cell_of(float x, float y, float z) {
  int a = (int)(x * (float)G_DIM);
  int b = (int)(y * (float)G_DIM);
  int c = (int)(z * (float)G_DIM);
  a = a < 0 ? 0 : (a > G_DIM-1 ? G_DIM-1 : a);
  b = b < 0 ? 0 : (b > G_DIM-1 ? G_DIM-1 : b);
  c = c < 0 ? 0 : (c > G_DIM-1 ? G_DIM-1 : c);
  return (a * G_DIM + b) * G_DIM + c;
}

// ---- DPP wave-wide reductions (ctrl must be a literal constant) ----
template <int CTRL>
__device__ __forceinline__ u32 dppmov_u(u32 v) {
  return (u32)__builtin_amdgcn_update_dpp((int)v, (int)v, CTRL, 0xf, 0xf, false);
}
template <int CTRL>
__device__ __forceinline__ float dppmov_f(float v) {
  return __int_as_float(
      __builtin_amdgcn_update_dpp(__float_as_int(v), __float_as_int(v),
                                  CTRL, 0xf, 0xf, false));
}
__device__ __forceinline__ float wave_max_f32(float v) {
  v = fmaxf(v, dppmov_f<0x111>(v));
  v = fmaxf(v, dppmov_f<0x112>(v));
  v = fmaxf(v, dppmov_f<0x114>(v));
  v = fmaxf(v, dppmov_f<0x118>(v));
  v = fmaxf(v, dppmov_f<0x142>(v));
  v = fmaxf(v, dppmov_f<0x143>(v));
  return __int_as_float(__builtin_amdgcn_readlane(__float_as_int(v), 63));
}
__device__ __forceinline__ float wave_min_f32(float v) {
  v = fminf(v, dppmov_f<0x111>(v));
  v = fminf(v, dppmov_f<0x112>(v));
  v = fminf(v, dppmov_f<0x114>(v));
  v = fminf(v, dppmov_f<0x118>(v));
  v = fminf(v, dppmov_f<0x142>(v));
  v = fminf(v, dppmov_f<0x143>(v));
  return __int_as_float(__builtin_amdgcn_readlane(__float_as_int(v), 63));
}
__device__ __forceinline__ u32 wave_min_u32(u32 v) {
  u32 t;
  t = dppmov_u<0x111>(v); v = v < t ? v : t;
  t = dppmov_u<0x112>(v); v = v < t ? v : t;
  t = dppmov_u<0x114>(v); v = v < t ? v : t;
  t = dppmov_u<0x118>(v); v = v < t ? v : t;
  t = dppmov_u<0x142>(v); v = v < t ? v : t;
  t = dppmov_u<0x143>(v); v = v < t ? v : t;
  return (u32)__builtin_amdgcn_readlane((int)v, 63);
}
template <int CTRL>
__device__ __forceinline__ u64 dpp_u64(u64 v) {
  u32 hi = dppmov_u<CTRL>((u32)(v >> 32));
  u32 lo = dppmov_u<CTRL>((u32)v);
  return ((u64)hi << 32) | (u64)lo;
}
__device__ __forceinline__ u64 wave_max_u64(u64 v) {
  u64 t;
  t = dpp_u64<0x111>(v); if (t > v) v = t;
  t = dpp_u64<0x112>(v); if (t > v) v = t;
  t = dpp_u64<0x114>(v); if (t > v) v = t;
  t = dpp_u64<0x118>(v); if (t > v) v = t;
  t = dpp_u64<0x142>(v); if (t > v) v = t;
  t = dpp_u64<0x143>(v); if (t > v) v = t;
  u32 rh = (u32)__builtin_amdgcn_readlane((int)(v >> 32), 63);
  u32 rl = (u32)__builtin_amdgcn_readlane((int)(v & 0xFFFFFFFFull), 63);
  return ((u64)rh << 32) | (u64)rl;
}

// ---------------- prep kernels ----------------
__global__ void init_zero_kernel(int* __restrict__ p, int n) {
  int t = blockIdx.x * blockDim.x + threadIdx.x;
  if (t < n) p[t] = 0;
}

__global__ void hist_kernel(const float* __restrict__ pos,
                            int* __restrict__ cellcnt) {
  int n = blockIdx.x * blockDim.x + threadIdx.x;
  if (n >= N_PTS) return;
  atomicAdd(&cellcnt[cell_of(pos[3*n], pos[3*n+1], pos[3*n+2])], 1);
}

__global__ __launch_bounds__(1024) void scan_kernel(
    const int* __restrict__ cellcnt, int* __restrict__ cursor,
    int2* __restrict__ rng, int* __restrict__ ncp)
{
  __shared__ int s[1024];
  const int tid = threadIdx.x;
  int cnt = (tid < N_CELL) ? cellcnt[tid] : 0;
  s[tid] = cnt;
  __syncthreads();
  for (int off = 1; off < 1024; off <<= 1) {        // inclusive scan (counts)
    int add = (tid >= off) ? s[tid - off] : 0;
    __syncthreads();
    s[tid] += add;
    __syncthreads();
  }
  int pofs = s[tid] - cnt;                          // exclusive point offset
  int nch  = (cnt + CHUNK_CAP - 1) / CHUNK_CAP;     // chunks for this cell
  __syncthreads();
  s[tid] = nch;
  __syncthreads();
  for (int off = 1; off < 1024; off <<= 1) {        // inclusive scan (chunks)
    int add = (tid >= off) ? s[tid - off] : 0;
    __syncthreads();
    s[tid] += add;
    __syncthreads();
  }
  int chbase = s[tid] - nch;
  if (tid < N_CELL) {
    cursor[tid] = pofs;
    for (int k = 0; k < nch; k++) {
      int rem = cnt - k * CHUNK_CAP;
      rng[chbase + k] = make_int2(pofs + k * CHUNK_CAP,
                                  rem < CHUNK_CAP ? rem : CHUNK_CAP);
    }
  }
  if (tid == 1023) *ncp = s[1023];                  // total chunk count
}

__global__ void scatter_kernel(const float* __restrict__ pos,
    int* __restrict__ cursor, float4* __restrict__ spp)
{
  int n = blockIdx.x * blockDim.x + threadIdx.x;
  if (n >= N_PTS) return;
  float x = pos[3*n], y = pos[3*n+1], z = pos[3*n+2];
  int p = atomicAdd(&cursor[cell_of(x, y, z)], 1);
  spp[p] = make_float4(x, y, z, __int_as_float(n));
}

__global__ __launch_bounds__(64) void bbox_kernel(
    const float4* __restrict__ spp, const int2* __restrict__ rng,
    const int* __restrict__ ncp,
    float4* __restrict__ bb_lo, float4* __restrict__ bb_hi,
    float* __restrict__ sdist)
{
  const int b = blockIdx.x, lane = threadIdx.x;
  int gid = b * 64 + lane;
  if (gid < NP_PAD) sdist[gid] = FLT_MAX;           // matches finfo(f32).max
  int NC = *ncp;
  if (b >= NC) return;
  int2 rc = rng[b];
  bool v0 = lane < rc.y, v1 = lane + 64 < rc.y;
  float4 P0 = v0 ? spp[rc.x + lane]      : make_float4(0,0,0,0);
  float4 P1 = v1 ? spp[rc.x + 64 + lane] : make_float4(0,0,0,0);
  float lx = wave_min_f32(fminf(v0 ? P0.x :  FLT_MAX, v1 ? P1.x :  FLT_MAX));
  float ly = wave_min_f32(fminf(v0 ? P0.y :  FLT_MAX, v1 ? P1.y :  FLT_MAX));
  float lz = wave_min_f32(fminf(v0 ? P0.z :  FLT_MAX, v1 ? P1.z :  FLT_MAX));
  float hx = wave_max_f32(fmaxf(v0 ? P0.x : -FLT_MAX, v1 ? P1.x : -FLT_MAX));
  float hy = wave_max_f32(fmaxf(v0 ? P0.y : -FLT_MAX, v1 ? P1.y : -FLT_MAX));
  float hz = wave_max_f32(fmaxf(v0 ? P0.z : -FLT_MAX, v1 ? P1.z : -FLT_MAX));
  if (lane == 0) {
    bb_lo[b] = make_float4(lx, ly, lz, 0.f);
    bb_hi[b] = make_float4(hx, hy, hz, 0.f);
  }
}

// ---------------- the FPS kernel ----------------
__global__ __launch_bounds__(FPS1_NT) void fps_kernel(
    const float* __restrict__ pos,
    const float4* __restrict__ spp, float* __restrict__ sdist,
    const int2* __restrict__ rng,
    const float4* __restrict__ bb_lo, const float4* __restrict__ bb_hi,
    const int* __restrict__ ncp, float* __restrict__ cent_out)
{
  __shared__ u64  l_key[NC_MAX];     // (maxdist_bits<<32) | ~minidx
  __shared__ int2 l_rng[NC_MAX];     // chunk (start, cnt)
  __shared__ int  l_act[NC_MAX];     // compacted active chunk ids
  __shared__ u64  l_red[NWAVE];
  __shared__ int  l_nact;
  __shared__ u32  l_win;

  const int tid = threadIdx.x, lane = tid & 63, wv = tid >> 6;
  const int NC = *ncp;               // <= 903 structurally (single pass)

  for (int c = tid; c < NC; c += FPS1_NT) {
    l_rng[c] = rng[c];
    l_key[c] = ((u64)0x7F7FFFFFu) << 32;   // maxdist = FLT_MAX: force update
  }
  __syncthreads();

  // iteration 0 centroid = point 0 (deterministic start, matches reference)
  float cx = pos[0], cy = pos[1], cz = pos[2];

  for (int i = 0; i < M_CENT; i++) {
    if (tid == 0) {
      cent_out[3*i+0] = cx; cent_out[3*i+1] = cy; cent_out[3*i+2] = cz;
      l_nact = 0;
    }
    if (i == M_CENT - 1) break;      // last winner never consumed (uniform)
    __syncthreads();

    // ---- Phase A: prune-eval + wave-ballot compaction (single pass) ----
    {
      int c = tid;
      bool act = false;
      if (c < NC) {
        float cmax = __uint_as_float((u32)(l_key[c] >> 32));
        float4 lo = bb_lo[c], hi = bb_hi[c];
        float ax = fmaxf(fmaxf(__fsub_rn(lo.x, cx), __fsub_rn(cx, hi.x)), 0.f);
        float ay = fmaxf(fmaxf(__fsub_rn(lo.y, cy), __fsub_rn(cy, hi.y)), 0.f);
        float az = fmaxf(fmaxf(__fsub_rn(lo.z, cz), __fsub_rn(cz, hi.z)), 0.f);
        float LB = (ax*ax + ay*ay + az*az) * 0.999f;  // conservative margin
        act = LB < cmax;             // NOT provably-skippable -> update
      }
      u64 m = __ballot(act);
      if (m) {
        int leader = __ffsll((long long)m) - 1;
        int base = 0;
        if (lane == leader) base = atomicAdd(&l_nact, __popcll(m));
        base = __shfl(base, leader, 64);
        if (act)
          l_act[base + __popcll(m & ((1ull << lane) - 1ull))] = c;
      }
    }
    __syncthreads();

    // ---- Phase B: update active chunks, one wave per 128-pt chunk ----
    int nact = l_nact;
    for (int a = wv; a < nact; a += NWAVE) {
      int c = l_act[a];
      int2 rc = l_rng[c];
      float d0 = -1.f, d1 = -1.f;
      u32 i0 = 0xFFFFFFFFu, i1 = 0xFFFFFFFFu;
      if (lane < rc.y) {
        int g = rc.x + lane;
        float4 P = spp[g];
        // exact reference arithmetic: no FMA, ((dx^2+dy^2)+dz^2)
        float dx = __fsub_rn(P.x, cx);
        float dy = __fsub_rn(P.y, cy);
        float dz = __fsub_rn(P.z, cz);
        float d2 = __fadd_rn(__fadd_rn(__fmul_rn(dx, dx), __fmul_rn(dy, dy)),
                             __fmul_rn(dz, dz));
        d0 = fminf(sdist[g], d2);
        sdist[g] = d0;
        i0 = (u32)__float_as_int(P.w);
      }
      if (lane + 64 < rc.y) {
        int g = rc.x + 64 + lane;
        float4 P = spp[g];
        float dx = __fsub_rn(P.x, cx);
        float dy = __fsub_rn(P.y, cy);
        float dz = __fsub_rn(P.z, cz);
        float d2 = __fadd_rn(__fadd_rn(__fmul_rn(dx, dx), __fmul_rn(dy, dy)),
                             __fmul_rn(dz, dz));
        d1 = fminf(sdist[g], d2);
        sdist[g] = d1;
        i1 = (u32)__float_as_int(P.w);
      }
      float wmax = wave_max_f32(fmaxf(d0, d1));   // >= 0: chunk non-empty
      u32 cand = 0xFFFFFFFFu;                     // min orig idx among ties
      if (d0 == wmax) cand = i0;
      if (d1 == wmax && i1 < cand) cand = i1;
      u32 minidx = wave_min_u32(cand);
      if (lane == 0)
        l_key[c] = ((u64)__float_as_uint(wmax) << 32) | (u64)(~minidx);
    }
    __syncthreads();

    // ---- Phase C: winner = max over all chunk keys (single pass) ----
    u64 best = (tid < NC) ? l_key[tid] : 0ull;
    best = wave_max_u64(best);
    if (lane == 0) l_red[wv] = best;
    __syncthreads();
    if (wv == 0) {
      u64 b = (lane < NWAVE) ? l_red[lane] : 0ull;
      b = wave_max_u64(b);
      if (lane == 0) l_win = ~(u32)(b & 0xFFFFFFFFull);
    }
    __syncthreads();
    u32 widx = l_win;                // orig index of winner
    cx = pos[3*widx+0]; cy = pos[3*widx+1]; cz = pos[3*widx+2];
  }
}

// ---------------- Ball query ----------------
#define BQ_NT  256
#define BQ_CAP 2048   // expected ~209 candidates/centroid; huge safety margin

__global__ __launch_bounds__(BQ_NT) void ballq_kernel(
    const float* __restrict__ pos,
    const float* __restrict__ cent,   // centroid coords (from d_out)
    int* __restrict__ nbr,            // [M_CENT*K_LOC]
    int* __restrict__ nsel)           // [M_CENT]
{
  __shared__ float s_d2[BQ_CAP];
  __shared__ int   s_idx[BQ_CAP];
  __shared__ int   s_count;
  __shared__ u64   s_red[BQ_NT/64];
  __shared__ u64   s_win;

  const int m = blockIdx.x, tid = threadIdx.x;
  if (tid == 0) s_count = 0;
  __syncthreads();
  const float cx = cent[3*m+0], cy = cent[3*m+1], cz = cent[3*m+2];

  for (int n = tid; n < N_PTS; n += BQ_NT) {
    float dx = __fsub_rn(cx, pos[3*n+0]);
    float dy = __fsub_rn(cy, pos[3*n+1]);
    float dz = __fsub_rn(cz, pos[3*n+2]);
    float d2 = __fadd_rn(__fadd_rn(__fmul_rn(dx,dx), __fmul_rn(dy,dy)),
                         __fmul_rn(dz,dz));
    if (d2 <= 0.01f) {   // same f32 value as (float)(0.1*0.1)
      int p = atomicAdd(&s_count, 1);
      if (p < BQ_CAP) { s_d2[p] = d2; s_idx[p] = n; }
    }
  }
  __syncthreads();
  int cnt = s_count; if (cnt > BQ_CAP) cnt = BQ_CAP;
  int ns = cnt < K_LOC ? cnt : K_LOC;

  // exact top_k semantics: k smallest d2, ties -> smaller index
  for (int sel = 0; sel < ns; sel++) {
    u64 best = ~0ull;
    for (int p = tid; p < cnt; p += BQ_NT) {
      u64 pk = ((u64)__float_as_uint(s_d2[p]) << 32) | (u64)(u32)s_idx[p];
      if (pk < best) best = pk;
    }
#pragma unroll
    for (int off = 32; off >= 1; off >>= 1) {
      u64 o = __shfl_down(best, off, 64);
      if (o < best) best = o;
    }
    if ((tid & 63) == 0) s_red[tid >> 6] = best;
    __syncthreads();
    if (tid < 64) {
      best = (tid < BQ_NT/64) ? s_red[tid] : ~0ull;
#pragma unroll
      for (int off = 2; off >= 1; off >>= 1) {
        u64 o = __shfl_down(best, off, 64);
        if (o < best) best = o;
      }
      if (tid == 0) s_win = best;
    }
    __syncthreads();
    int widx = (int)(u32)(s_win & 0xFFFFFFFFull);
    if (tid == 0) nbr[m*K_LOC + sel] = widx;
    for (int p = tid; p < cnt; p += BQ_NT) {
      if (s_idx[p] == widx) s_d2[p] = FLT_MAX;   // remove winner
    }
    __syncthreads();
  }
  if (tid == 0) nsel[m] = ns;
}

// ---------------- Gather + max-pool + channel mix ----------------
// Max over the valid selected set == reference (fallback idx is the nearest
// valid neighbor, already a member of the set).
__global__ __launch_bounds__(C_CH) void pool_mix_kernel(
    const float* __restrict__ fs,   // (N,128,1)
    const float* __restrict__ fv,   // (N,128,3)
    const float* __restrict__ Ws,
    const float* __restrict__ Wv,
    const float* __restrict__ bs,
    const float* __restrict__ bv,
    const int* __restrict__ nbr,
    const int* __restrict__ nsel,
    float* __restrict__ out_s,      // (M,128,1)
    float* __restrict__ out_v)      // (M,128,3)
{
  __shared__ float ps[C_CH];
  __shared__ float pv[C_CH*3];
  const int m = blockIdx.x, o = threadIdx.x;
  const int ns = nsel[m];
  float mS = -FLT_MAX, m0 = -FLT_MAX, m1 = -FLT_MAX, m2 = -FLT_MAX;
  for (int j = 0; j < ns; j++) {
    int n = nbr[m*K_LOC + j];
    mS = fmaxf(mS, fs[(size_t)n*C_CH + o]);
    const float* r = fv + (size_t)n*(C_CH*3) + 3*o;
    m0 = fmaxf(m0, r[0]); m1 = fmaxf(m1, r[1]); m2 = fmaxf(m2, r[2]);
  }
  ps[o] = mS; pv[3*o+0] = m0; pv[3*o+1] = m1; pv[3*o+2] = m2;
  __syncthreads();
  float aS = bs[o];
  float a0 = bv[o], a1 = bv[o], a2 = bv[o];
  for (int cc = 0; cc < C_CH; cc++) {
    float w1 = Ws[cc*C_CH + o];
    float w2 = Wv[cc*C_CH + o];
    aS = fmaf(ps[cc], w1, aS);
    a0 = fmaf(pv[3*cc+0], w2, a0);
    a1 = fmaf(pv[3*cc+1], w2, a1);
    a2 = fmaf(pv[3*cc+2], w2, a2);
  }
  out_s[(size_t)m*C_CH + o] = aS;
  float* ov = out_v + (size_t)m*(C_CH*3) + 3*o;
  ov[0] = a0; ov[1] = a1; ov[2] = a2;
}

extern "C" void kernel_launch(void* const* d_in, const int* in_sizes, int n_in,
                              void* d_out, int out_size, void* d_ws, size_t ws_size,
                              hipStream_t stream) {
  (void)in_sizes; (void)n_in; (void)out_size; (void)ws_size;
  const float* pos = (const float*)d_in[0];
  const float* fs  = (const float*)d_in[1];
  const float* fv  = (const float*)d_in[2];
  const float* Ws  = (const float*)d_in[3];
  const float* Wv  = (const float*)d_in[4];
  const float* bs  = (const float*)d_in[5];
  const float* bv  = (const float*)d_in[6];

  float* out      = (float*)d_out;
  float* cent_out = out;                               // 2048*3
  float* out_s    = out + 3*M_CENT;                    // 2048*128
  float* out_v    = out + 3*M_CENT + M_CENT*C_CH;      // 2048*128*3

  // workspace layout (all offsets 256B-aligned)
  char* ws = (char*)d_ws;
  size_t off = 0;
  float4* spp  = (float4*)(ws + off); off += (size_t)NP_PAD * 16;  // 802816
  float* sdist = (float*)(ws + off);  off += (size_t)NP_PAD * 4;
  int*   cellcnt = (int*)(ws + off);  off += 1024 * 4;
  int*   cursor  = (int*)(ws + off);  off += 1024 * 4;
  int*   ncp     = (int*)(ws + off);  off += 256;
  int2*  rng     = (int2*)(ws + off); off += (size_t)NC_MAX * 8;
  float4* bb_lo  = (float4*)(ws + off); off += (size_t)NC_MAX * 16;
  float4* bb_hi  = (float4*)(ws + off); off += (size_t)NC_MAX * 16;
  int*   nbr     = (int*)(ws + off); off += (size_t)M_CENT * K_LOC * 4;
  int*   nsel    = (int*)(ws + off); off += (size_t)M_CENT * 4;

  // zero cellcnt + cursor + ncp (contiguous: 1024+1024+64 ints)
  init_zero_kernel<<<(2112 + 255)/256, 256, 0, stream>>>(cellcnt, 2112);
  hist_kernel<<<(N_PTS + 255)/256, 256, 0, stream>>>(pos, cellcnt);
  scan_kernel<<<1, 1024, 0, stream>>>(cellcnt, cursor, rng, ncp);
  scatter_kernel<<<(N_PTS + 255)/256, 256, 0, stream>>>(pos, cursor, spp);
  bbox_kernel<<<NC_MAX, 64, 0, stream>>>(spp, rng, ncp, bb_lo, bb_hi, sdist);
  fps_kernel<<<1, FPS1_NT, 0, stream>>>(pos, spp, sdist, rng,
                                        bb_lo, bb_hi, ncp, cent_out);
  ballq_kernel<<<M_CENT, BQ_NT, 0, stream>>>(pos, cent_out, nbr, nsel);
  pool_mix_kernel<<<M_CENT, C_CH, 0, stream>>>(fs, fv, Ws, Wv, bs, bv,
                                               nbr, nsel, out_s, out_v);
}